// Round 11
// baseline (81.597 us; speedup 1.0000x reference)
//
#include <hip/hip_runtime.h>

// Chamfer via MFMA. d2 = psq + qsq - 2 p.q in ONE v_mfma_f32_32x32x16_bf16
// per 32x32 tile (packing PROVEN R6-R10, absmax 0.0):
//   A k: {psqh,psql,-2ph(y,z,w),-2pl(y,z,w) | -2ph(y,z,w),1,1,0,0,0}
//   B k: {1,1,qh(y,z,w),qh(y,z,w) | ql(y,z,w),qsqh,qsql,0,0,0}
// Occupancy-first layout: grid = 128 batches x 2 dirs x 2 col-halves x
// 2 ROW-halves = 1024 blocks x 256 thr. A-tile = 512 rows -> LDS 32 KB and
// launch_bounds(256,4) -> 4 blocks/CU = 4 waves/SIMD (2x R10) so MFMA and
// min3 phases of different waves co-schedule (m114).
// Inner loop unchanged: 2 row-tiles x 4 col-tiles/wave per step,
// elementwise min3 folds in C layout, no in-loop reductions.
// Col-min per block is PARTIAL (512 of 1024 rows): per-col partials ->
// ws (non-atomic, [dirbatchcol][rb] float2 layout, 2 MB).
// Final kernel: min of rb-pair, clamp+eps+sqrt, sum, atomicAdd.

typedef short bf16x8 __attribute__((ext_vector_type(8)));
typedef float f32x16 __attribute__((ext_vector_type(16)));

#define ONE_BF 0x3f80

__device__ __forceinline__ unsigned short f2bf(float x) {
    unsigned u = __float_as_uint(x);
    u += 0x7fffu + ((u >> 16) & 1u);          // round-to-nearest-even
    return (unsigned short)(u >> 16);
}
__device__ __forceinline__ float bf2f(unsigned short h) {
    return __uint_as_float(((unsigned)h) << 16);
}

__global__ __launch_bounds__(256, 4) void chamfer_main(
    const float4* __restrict__ P, const float4* __restrict__ Q,
    float* __restrict__ part)
{
    __shared__ short lAh[512 * 8];    // A k-slots 0-7  (8 KB)
    __shared__ short lAl[512 * 8];    // A k-slots 8-15 (8 KB)
    __shared__ short lB[512 * 16];    // B interleaved [pt][half][8] (16 KB)

    const int blk   = blockIdx.x;
    const int batch = blk >> 3;        // 0..127
    const int dir   = (blk >> 2) & 1;  // 0: rows=P cols=Q; 1: swapped
    const int cb    = (blk >> 1) & 1;  // col-half (512 cols)
    const int rb    = blk & 1;         // row-half (512 rows)
    const int t     = threadIdx.x;
    const int base  = batch << 10;

    const float4* __restrict__ ownb = (dir ? Q : P) + base;   // rows
    const float4* __restrict__ oppb = (dir ? P : Q) + base;   // cols

    // ---- Pack this block's 512 rows into LDS A-fragments: 2 pts/thread ----
#pragma unroll
    for (int i = 0; i < 2; ++i) {
        const int pt = t + (i << 8);              // local row 0..511
        float4 v = ownb[(rb << 9) + pt];
        float psq = v.y * v.y + v.z * v.z + v.w * v.w;
        unsigned short psqh = f2bf(psq);
        unsigned short psql = f2bf(psq - bf2f(psqh));
        unsigned short yh = f2bf(v.y), zh = f2bf(v.z), wh = f2bf(v.w);
        unsigned short m2yh = f2bf(-2.0f * bf2f(yh));
        unsigned short m2zh = f2bf(-2.0f * bf2f(zh));
        unsigned short m2wh = f2bf(-2.0f * bf2f(wh));
        unsigned short m2yl = f2bf(-2.0f * (v.y - bf2f(yh)));
        unsigned short m2zl = f2bf(-2.0f * (v.z - bf2f(zh)));
        unsigned short m2wl = f2bf(-2.0f * (v.w - bf2f(wh)));
        bf16x8 ah = { (short)psqh, (short)psql, (short)m2yh, (short)m2zh,
                      (short)m2wh, (short)m2yl, (short)m2zl, (short)m2wl };
        bf16x8 al = { (short)m2yh, (short)m2zh, (short)m2wh,
                      (short)ONE_BF, (short)ONE_BF, 0, 0, 0 };
        *(bf16x8*)&lAh[pt * 8] = ah;
        *(bf16x8*)&lAl[pt * 8] = al;
    }
    // ---- Pack this block's 512 cols into LDS B-fragments: 2 pts/thread ----
#pragma unroll
    for (int i = 0; i < 2; ++i) {
        const int pt = t + (i << 8);              // local col 0..511
        float4 v = oppb[(cb << 9) + pt];
        float qsq = v.y * v.y + v.z * v.z + v.w * v.w;
        unsigned short qsqh = f2bf(qsq);
        unsigned short qsql = f2bf(qsq - bf2f(qsqh));
        unsigned short yh = f2bf(v.y), zh = f2bf(v.z), wh = f2bf(v.w);
        unsigned short yl = f2bf(v.y - bf2f(yh));
        unsigned short zl = f2bf(v.z - bf2f(zh));
        unsigned short wl = f2bf(v.w - bf2f(wh));
        bf16x8 bh = { (short)ONE_BF, (short)ONE_BF, (short)yh, (short)zh,
                      (short)wh, (short)yh, (short)zh, (short)wh };
        bf16x8 bl = { (short)yl, (short)zl, (short)wl,
                      (short)qsqh, (short)qsql, 0, 0, 0 };
        *(bf16x8*)&lB[pt * 16]     = bh;
        *(bf16x8*)&lB[pt * 16 + 8] = bl;
    }
    __syncthreads();

    const int lane = t & 63;
    const int half = lane >> 5;    // k-half: 0 -> slots 0-7, 1 -> 8-15
    const int l31  = lane & 31;
    const int wv   = t >> 6;

    const short* aptr = half ? lAl : lAh;

    // Four local col-tiles per wave.
    bf16x8 bf[4];
#pragma unroll
    for (int k = 0; k < 4; ++k) {
        const int pt = ((wv << 2) + k) * 32 + l31;
        bf[k] = *(const bf16x8*)&lB[(pt * 2 + half) * 8];
    }

    f32x16 zf;
#pragma unroll
    for (int j = 0; j < 16; ++j) zf[j] = 0.0f;

    f32x16 acc[4];
#pragma unroll
    for (int k = 0; k < 4; ++k)
#pragma unroll
        for (int j = 0; j < 16; ++j) acc[k][j] = 3.4e38f;

    // Inner: 2 row-tiles x 4 col-tiles per step over 16 row-tiles.
    for (int rt = 0; rt < 16; rt += 2) {
        bf16x8 af0 = *(const bf16x8*)&aptr[((rt << 5) + l31) * 8];
        bf16x8 af1 = *(const bf16x8*)&aptr[(((rt + 1) << 5) + l31) * 8];
#pragma unroll
        for (int k = 0; k < 4; ++k) {
            f32x16 ca = __builtin_amdgcn_mfma_f32_32x32x16_bf16(af0, bf[k], zf, 0, 0, 0);
            f32x16 cb2 = __builtin_amdgcn_mfma_f32_32x32x16_bf16(af1, bf[k], zf, 0, 0, 0);
#pragma unroll
            for (int j = 0; j < 16; ++j)
                acc[k][j] = fminf(fminf(ca[j], cb2[j]), acc[k][j]);  // v_min3
        }
    }

    // Epilogue: per col-tile 16->1 tree + cross-half shfl; half 0 stores the
    // per-col PARTIAL min (over this block's 512 rows) to ws.
#pragma unroll
    for (int k = 0; k < 4; ++k) {
        float m = acc[k][0];
#pragma unroll
        for (int j = 1; j < 16; ++j) m = fminf(m, acc[k][j]);
        m = fminf(m, __shfl_xor(m, 32, 64));
        if (half == 0) {
            const int gcol = (cb << 9) + ((wv << 2) + k) * 32 + l31;
            const int p = (((dir << 7) + batch) << 10) + gcol;
            part[p * 2 + rb] = m;
        }
    }
}

__global__ __launch_bounds__(256) void chamfer_final(
    const float2* __restrict__ part, float* __restrict__ out)
{
    __shared__ float ws[4];
    const int t = threadIdx.x;
    float s = 0.0f;
    // 2 dirs * 128 batches * 1024 cols = 2^18 slots, each a float2 (rb pair)
    for (int i = blockIdx.x * 256 + t; i < (1 << 18); i += 128 * 256) {
        float2 v = part[i];
        float m = fminf(v.x, v.y);
        s += sqrtf(fmaxf(m, 0.0f) + 1e-12f);
    }
#pragma unroll
    for (int off = 32; off; off >>= 1) s += __shfl_down(s, off, 64);
    if ((t & 63) == 0) ws[t >> 6] = s;
    __syncthreads();
    if (t == 0) atomicAdd(out, ws[0] + ws[1] + ws[2] + ws[3]);
}

extern "C" void kernel_launch(void* const* d_in, const int* in_sizes, int n_in,
                              void* d_out, int out_size, void* d_ws, size_t ws_size,
                              hipStream_t stream) {
    const float4* P = (const float4*)d_in[0];
    const float4* Q = (const float4*)d_in[1];
    float* out  = (float*)d_out;
    float* part = (float*)d_ws;   // 2^18 slots x float2 = 2 MB

    hipMemsetAsync(d_out, 0, sizeof(float), stream);
    chamfer_main<<<dim3(128 * 2 * 2 * 2), dim3(256), 0, stream>>>(P, Q, part);
    chamfer_final<<<dim3(128), dim3(256), 0, stream>>>((const float2*)part, out);
}

// Round 12
// 77.059 us; speedup vs baseline: 1.0589x; 1.0589x over previous
//
#include <hip/hip_runtime.h>

// Chamfer via MFMA — final consolidated version (R9 compute shape, fused
// finish). d2 = psq + qsq - 2 p.q in ONE v_mfma_f32_32x32x16_bf16 per
// 32x32 tile (packing PROVEN R6-R11, absmax 0.0):
//   A k: {psqh,psql,-2ph(y,z,w),-2pl(y,z,w) | -2ph(y,z,w),1,1,0,0,0}
//   B k: {1,1,qh(y,z,w),qh(y,z,w) | ql(y,z,w),qsqh,qsql,0,0,0}
// Grid: 128 batches x 2 dirs x 4 col-blocks = 1024 blocks x 256 thr
// (4 waves x 2 col-tiles; 40 KB LDS -> 4 blocks/CU, VGPR ~88).
// Inner loop: 2 row-tiles x 2 col-tiles per step, elementwise min3 folds in
// C layout, no in-loop reductions. Epilogue: 16->1 min tree, shfl_xor(32),
// sqrt, wave+block sum, ONE atomicAdd per block (512 staggered atomics
// total — measured negligible in R10). No second kernel, no ws.

typedef short bf16x8 __attribute__((ext_vector_type(8)));
typedef float f32x16 __attribute__((ext_vector_type(16)));

#define ONE_BF 0x3f80

__device__ __forceinline__ unsigned short f2bf(float x) {
    unsigned u = __float_as_uint(x);
    u += 0x7fffu + ((u >> 16) & 1u);          // round-to-nearest-even
    return (unsigned short)(u >> 16);
}
__device__ __forceinline__ float bf2f(unsigned short h) {
    return __uint_as_float(((unsigned)h) << 16);
}

__global__ __launch_bounds__(256, 3) void chamfer_dir(
    const float4* __restrict__ P, const float4* __restrict__ Q,
    float* __restrict__ out)
{
    __shared__ short lAh[1024 * 8];   // A k-slots 0-7  (16 KB)
    __shared__ short lAl[1024 * 8];   // A k-slots 8-15 (16 KB)
    __shared__ short lB[256 * 16];    // B interleaved [pt][half][8] (8 KB)
    __shared__ float wsum[4];

    const int blk   = blockIdx.x;
    const int batch = blk >> 3;        // 0..127
    const int dir   = (blk >> 2) & 1;  // 0: rows=P cols=Q; 1: swapped
    const int cb    = blk & 3;         // col-block (256 cols each)
    const int t     = threadIdx.x;
    const int base  = batch << 10;

    const float4* __restrict__ ownb = (dir ? Q : P) + base;   // rows
    const float4* __restrict__ oppb = (dir ? P : Q) + base;   // cols

    // ---- Pack rows (full cloud) into LDS A-fragments: 4 pts/thread ----
#pragma unroll
    for (int i = 0; i < 4; ++i) {
        const int pt = t + (i << 8);
        float4 v = ownb[pt];
        float psq = v.y * v.y + v.z * v.z + v.w * v.w;
        unsigned short psqh = f2bf(psq);
        unsigned short psql = f2bf(psq - bf2f(psqh));
        unsigned short yh = f2bf(v.y), zh = f2bf(v.z), wh = f2bf(v.w);
        unsigned short m2yh = f2bf(-2.0f * bf2f(yh));
        unsigned short m2zh = f2bf(-2.0f * bf2f(zh));
        unsigned short m2wh = f2bf(-2.0f * bf2f(wh));
        unsigned short m2yl = f2bf(-2.0f * (v.y - bf2f(yh)));
        unsigned short m2zl = f2bf(-2.0f * (v.z - bf2f(zh)));
        unsigned short m2wl = f2bf(-2.0f * (v.w - bf2f(wh)));
        bf16x8 ah = { (short)psqh, (short)psql, (short)m2yh, (short)m2zh,
                      (short)m2wh, (short)m2yl, (short)m2zl, (short)m2wl };
        bf16x8 al = { (short)m2yh, (short)m2zh, (short)m2wh,
                      (short)ONE_BF, (short)ONE_BF, 0, 0, 0 };
        *(bf16x8*)&lAh[pt * 8] = ah;
        *(bf16x8*)&lAl[pt * 8] = al;
    }
    // ---- Pack this block's 256 cols into LDS B-fragments ----
    {
        float4 v = oppb[(cb << 8) + t];
        float qsq = v.y * v.y + v.z * v.z + v.w * v.w;
        unsigned short qsqh = f2bf(qsq);
        unsigned short qsql = f2bf(qsq - bf2f(qsqh));
        unsigned short yh = f2bf(v.y), zh = f2bf(v.z), wh = f2bf(v.w);
        unsigned short yl = f2bf(v.y - bf2f(yh));
        unsigned short zl = f2bf(v.z - bf2f(zh));
        unsigned short wl = f2bf(v.w - bf2f(wh));
        bf16x8 bh = { (short)ONE_BF, (short)ONE_BF, (short)yh, (short)zh,
                      (short)wh, (short)yh, (short)zh, (short)wh };
        bf16x8 bl = { (short)yl, (short)zl, (short)wl,
                      (short)qsqh, (short)qsql, 0, 0, 0 };
        *(bf16x8*)&lB[t * 16]     = bh;
        *(bf16x8*)&lB[t * 16 + 8] = bl;
    }
    __syncthreads();

    const int lane = t & 63;
    const int half = lane >> 5;    // k-half: 0 -> slots 0-7, 1 -> 8-15
    const int l31  = lane & 31;
    const int wv   = t >> 6;

    const short* aptr = half ? lAl : lAh;

    // Two local col-tiles per wave: c0 = wv*2, c0+1
    const int c0 = wv << 1;
    bf16x8 bf0 = *(const bf16x8*)&lB[(((c0 << 5) + l31) * 2 + half) * 8];
    bf16x8 bf1 = *(const bf16x8*)&lB[((((c0 + 1) << 5) + l31) * 2 + half) * 8];

    f32x16 zf;
#pragma unroll
    for (int j = 0; j < 16; ++j) zf[j] = 0.0f;

    f32x16 acc0, acc1;
#pragma unroll
    for (int j = 0; j < 16; ++j) { acc0[j] = 3.4e38f; acc1[j] = 3.4e38f; }

    // Inner loop: 2 row-tiles/step, elementwise min3 fold, NO reductions.
    for (int rt = 0; rt < 32; rt += 2) {
        bf16x8 af0 = *(const bf16x8*)&aptr[((rt << 5) + l31) * 8];
        bf16x8 af1 = *(const bf16x8*)&aptr[(((rt + 1) << 5) + l31) * 8];
        f32x16 ca0 = __builtin_amdgcn_mfma_f32_32x32x16_bf16(af0, bf0, zf, 0, 0, 0);
        f32x16 cb0 = __builtin_amdgcn_mfma_f32_32x32x16_bf16(af1, bf0, zf, 0, 0, 0);
        f32x16 ca1 = __builtin_amdgcn_mfma_f32_32x32x16_bf16(af0, bf1, zf, 0, 0, 0);
        f32x16 cb1 = __builtin_amdgcn_mfma_f32_32x32x16_bf16(af1, bf1, zf, 0, 0, 0);
#pragma unroll
        for (int j = 0; j < 16; ++j)
            acc0[j] = fminf(fminf(ca0[j], cb0[j]), acc0[j]);   // v_min3_f32
#pragma unroll
        for (int j = 0; j < 16; ++j)
            acc1[j] = fminf(fminf(ca1[j], cb1[j]), acc1[j]);
    }

    // Epilogue: 16->1 tree, cross-half shfl, sqrt, wave-sum, one atomic.
    float m0 = acc0[0], m1 = acc1[0];
#pragma unroll
    for (int j = 1; j < 16; ++j) { m0 = fminf(m0, acc0[j]); m1 = fminf(m1, acc1[j]); }
    m0 = fminf(m0, __shfl_xor(m0, 32, 64));
    m1 = fminf(m1, __shfl_xor(m1, 32, 64));

    float s = 0.0f;
    if (half == 0)
        s = sqrtf(fmaxf(m0, 0.0f) + 1e-12f) + sqrtf(fmaxf(m1, 0.0f) + 1e-12f);
#pragma unroll
    for (int off = 32; off; off >>= 1) s += __shfl_down(s, off, 64);
    if (lane == 0) wsum[wv] = s;
    __syncthreads();
    if (t == 0) atomicAdd(out, wsum[0] + wsum[1] + wsum[2] + wsum[3]);
}

extern "C" void kernel_launch(void* const* d_in, const int* in_sizes, int n_in,
                              void* d_out, int out_size, void* d_ws, size_t ws_size,
                              hipStream_t stream) {
    const float4* P = (const float4*)d_in[0];
    const float4* Q = (const float4*)d_in[1];
    float* out = (float*)d_out;

    hipMemsetAsync(d_out, 0, sizeof(float), stream);
    chamfer_dir<<<dim3(128 * 2 * 4), dim3(256), 0, stream>>>(P, Q, out);
}

// Round 13
// 69.900 us; speedup vs baseline: 1.1673x; 1.1024x over previous
//
#include <hip/hip_runtime.h>

// Chamfer via MFMA — EXACT R9 revert (best measured: 70.29 µs).
// d2 = psq + qsq - 2 p.q in ONE v_mfma_f32_32x32x16_bf16 per 32x32 tile
// (packing PROVEN R6-R12, absmax 0.0):
//   A k: {psqh,psql,-2ph(y,z,w),-2pl(y,z,w) | -2ph(y,z,w),1,1,0,0,0}
//   B k: {1,1,qh(y,z,w),qh(y,z,w) | ql(y,z,w),qsqh,qsql,0,0,0}
// Two passes over tile space (dir 0/1). Inner loop does NO reduction:
// col-partial mins accumulate ELEMENTWISE in C layout, two row-tiles per
// step folded with v_min3 (8 VALU/tile). The 16->1 tree + single
// shfl_xor(32) + sqrt run once per wave in the epilogue.
// Grid: 128 batches x 2 dirs x 4 col-blocks = 1024 blocks x 256 thr
// (4 waves x 2 col-tiles each). LDS 40KB -> 4 blocks/CU.
// Non-atomic block partials -> ws; 1-block final kernel sums them
// (per-block atomicAdd REGRESSES: 1024 co-resident blocks finish together
// -> same-address atomic herd, +7 µs measured in R12).

typedef short bf16x8 __attribute__((ext_vector_type(8)));
typedef float f32x16 __attribute__((ext_vector_type(16)));

#define ONE_BF 0x3f80

__device__ __forceinline__ unsigned short f2bf(float x) {
    unsigned u = __float_as_uint(x);
    u += 0x7fffu + ((u >> 16) & 1u);          // round-to-nearest-even
    return (unsigned short)(u >> 16);
}
__device__ __forceinline__ float bf2f(unsigned short h) {
    return __uint_as_float(((unsigned)h) << 16);
}

__global__ __launch_bounds__(256, 3) void chamfer_dir(
    const float4* __restrict__ P, const float4* __restrict__ Q,
    float* __restrict__ part)
{
    __shared__ short lAh[1024 * 8];   // A k-slots 0-7  (16 KB)
    __shared__ short lAl[1024 * 8];   // A k-slots 8-15 (16 KB)
    __shared__ short lB[256 * 16];    // B interleaved [pt][half][8] (8 KB)
    __shared__ float wsum[4];

    const int blk   = blockIdx.x;
    const int batch = blk >> 3;        // 0..127
    const int dir   = (blk >> 2) & 1;  // 0: rows=P cols=Q; 1: swapped
    const int cb    = blk & 3;         // col-block (256 cols each)
    const int t     = threadIdx.x;
    const int base  = batch << 10;

    const float4* __restrict__ ownb = (dir ? Q : P) + base;   // rows
    const float4* __restrict__ oppb = (dir ? P : Q) + base;   // cols

    // ---- Pack rows (full cloud) into LDS A-fragments: 4 pts/thread ----
#pragma unroll
    for (int i = 0; i < 4; ++i) {
        const int pt = t + (i << 8);
        float4 v = ownb[pt];
        float psq = v.y * v.y + v.z * v.z + v.w * v.w;
        unsigned short psqh = f2bf(psq);
        unsigned short psql = f2bf(psq - bf2f(psqh));
        unsigned short yh = f2bf(v.y), zh = f2bf(v.z), wh = f2bf(v.w);
        unsigned short m2yh = f2bf(-2.0f * bf2f(yh));
        unsigned short m2zh = f2bf(-2.0f * bf2f(zh));
        unsigned short m2wh = f2bf(-2.0f * bf2f(wh));
        unsigned short m2yl = f2bf(-2.0f * (v.y - bf2f(yh)));
        unsigned short m2zl = f2bf(-2.0f * (v.z - bf2f(zh)));
        unsigned short m2wl = f2bf(-2.0f * (v.w - bf2f(wh)));
        bf16x8 ah = { (short)psqh, (short)psql, (short)m2yh, (short)m2zh,
                      (short)m2wh, (short)m2yl, (short)m2zl, (short)m2wl };
        bf16x8 al = { (short)m2yh, (short)m2zh, (short)m2wh,
                      (short)ONE_BF, (short)ONE_BF, 0, 0, 0 };
        *(bf16x8*)&lAh[pt * 8] = ah;
        *(bf16x8*)&lAl[pt * 8] = al;
    }
    // ---- Pack this block's 256 cols into LDS B-fragments ----
    {
        float4 v = oppb[(cb << 8) + t];
        float qsq = v.y * v.y + v.z * v.z + v.w * v.w;
        unsigned short qsqh = f2bf(qsq);
        unsigned short qsql = f2bf(qsq - bf2f(qsqh));
        unsigned short yh = f2bf(v.y), zh = f2bf(v.z), wh = f2bf(v.w);
        unsigned short yl = f2bf(v.y - bf2f(yh));
        unsigned short zl = f2bf(v.z - bf2f(zh));
        unsigned short wl = f2bf(v.w - bf2f(wh));
        bf16x8 bh = { (short)ONE_BF, (short)ONE_BF, (short)yh, (short)zh,
                      (short)wh, (short)yh, (short)zh, (short)wh };
        bf16x8 bl = { (short)yl, (short)zl, (short)wl,
                      (short)qsqh, (short)qsql, 0, 0, 0 };
        *(bf16x8*)&lB[t * 16]     = bh;
        *(bf16x8*)&lB[t * 16 + 8] = bl;
    }
    __syncthreads();

    const int lane = t & 63;
    const int half = lane >> 5;    // k-half: 0 -> slots 0-7, 1 -> 8-15
    const int l31  = lane & 31;
    const int wv   = t >> 6;

    const short* aptr = half ? lAl : lAh;

    // Two local col-tiles per wave: c0 = wv*2, c0+1
    const int c0 = wv << 1;
    bf16x8 bf0 = *(const bf16x8*)&lB[(((c0 << 5) + l31) * 2 + half) * 8];
    bf16x8 bf1 = *(const bf16x8*)&lB[((((c0 + 1) << 5) + l31) * 2 + half) * 8];

    f32x16 zf;
#pragma unroll
    for (int j = 0; j < 16; ++j) zf[j] = 0.0f;

    f32x16 acc0, acc1;
#pragma unroll
    for (int j = 0; j < 16; ++j) { acc0[j] = 3.4e38f; acc1[j] = 3.4e38f; }

    // Inner loop: 2 row-tiles/step, elementwise min3 fold, NO reductions.
    for (int rt = 0; rt < 32; rt += 2) {
        bf16x8 af0 = *(const bf16x8*)&aptr[((rt << 5) + l31) * 8];
        bf16x8 af1 = *(const bf16x8*)&aptr[(((rt + 1) << 5) + l31) * 8];
        f32x16 ca0 = __builtin_amdgcn_mfma_f32_32x32x16_bf16(af0, bf0, zf, 0, 0, 0);
        f32x16 cb0 = __builtin_amdgcn_mfma_f32_32x32x16_bf16(af1, bf0, zf, 0, 0, 0);
        f32x16 ca1 = __builtin_amdgcn_mfma_f32_32x32x16_bf16(af0, bf1, zf, 0, 0, 0);
        f32x16 cb1 = __builtin_amdgcn_mfma_f32_32x32x16_bf16(af1, bf1, zf, 0, 0, 0);
#pragma unroll
        for (int j = 0; j < 16; ++j)
            acc0[j] = fminf(fminf(ca0[j], cb0[j]), acc0[j]);   // v_min3_f32
#pragma unroll
        for (int j = 0; j < 16; ++j)
            acc1[j] = fminf(fminf(ca1[j], cb1[j]), acc1[j]);
    }

    // Epilogue: 16->1 tree, cross-half shfl, sqrt, wave-sum, block partial.
    float m0 = acc0[0], m1 = acc1[0];
#pragma unroll
    for (int j = 1; j < 16; ++j) { m0 = fminf(m0, acc0[j]); m1 = fminf(m1, acc1[j]); }
    m0 = fminf(m0, __shfl_xor(m0, 32, 64));
    m1 = fminf(m1, __shfl_xor(m1, 32, 64));

    float s = 0.0f;
    if (half == 0)
        s = sqrtf(fmaxf(m0, 0.0f) + 1e-12f) + sqrtf(fmaxf(m1, 0.0f) + 1e-12f);
#pragma unroll
    for (int off = 32; off; off >>= 1) s += __shfl_down(s, off, 64);
    if (lane == 0) wsum[wv] = s;
    __syncthreads();
    if (t == 0) part[blk] = wsum[0] + wsum[1] + wsum[2] + wsum[3];
}

__global__ __launch_bounds__(256) void chamfer_final(
    const float* __restrict__ part, float* __restrict__ out)
{
    __shared__ float ws[4];
    const int t = threadIdx.x;
    float s = part[t] + part[t + 256] + part[t + 512] + part[t + 768];
#pragma unroll
    for (int off = 32; off; off >>= 1) s += __shfl_down(s, off, 64);
    if ((t & 63) == 0) ws[t >> 6] = s;
    __syncthreads();
    if (t == 0) out[0] = ws[0] + ws[1] + ws[2] + ws[3];
}

extern "C" void kernel_launch(void* const* d_in, const int* in_sizes, int n_in,
                              void* d_out, int out_size, void* d_ws, size_t ws_size,
                              hipStream_t stream) {
    const float4* P = (const float4*)d_in[0];
    const float4* Q = (const float4*)d_in[1];
    float* out  = (float*)d_out;
    float* part = (float*)d_ws;   // 1024 block partials (4 KB)

    chamfer_dir<<<dim3(128 * 2 * 4), dim3(256), 0, stream>>>(P, Q, part);
    chamfer_final<<<dim3(1), dim3(256), 0, stream>>>(part, out);
}